// Round 2
// baseline (489.693 us; speedup 1.0000x reference)
//
#include <hip/hip_runtime.h>
#include <math.h>

#define BB 8
#define NN 2048
#define SS 16
#define CC 32
#define DD 128

typedef unsigned short u16;
typedef __attribute__((ext_vector_type(8))) short bf16x8;
typedef __attribute__((ext_vector_type(4))) float f32x4;

__device__ inline u16 f2bf(float f) {
    union { float f; unsigned u; } c; c.f = f;
    unsigned r = c.u + 0x7fff + ((c.u >> 16) & 1);   // round-to-nearest-even
    return (u16)(r >> 16);
}
__device__ inline float bf2f(u16 h) {
    union { unsigned u; float f; } c; c.u = ((unsigned)h) << 16;
    return c.f;
}
__device__ inline u16 f2h(float f) {
    union { _Float16 h; u16 u; } c; c.h = (_Float16)f;
    return c.u;
}
__device__ inline float h2f(u16 u) {
    union { _Float16 h; u16 v; } c; c.v = u;
    return (float)c.h;
}
__device__ inline float clamp01(float v) { return fminf(fmaxf(v, 0.f), 1.f); }

// ---------------- K1: merged prep: bias tables + wcomb + wlt ---------------
// blocks 0..4095: bias_prep (lgh f16 -inf-masked, am bf16)
// block 4096: Wpq = Wproj@Wq, Wpk = Wproj@Wk ; block 4097: WlT = bf16(Wlin^T)
__global__ __launch_bounds__(256) void prep_kernel(const float* __restrict__ Astat,
                                                   const int* __restrict__ Mm,
                                                   const float* __restrict__ Wproj,
                                                   const float* __restrict__ Wq,
                                                   const float* __restrict__ Wk,
                                                   const float* __restrict__ Wl,
                                                   u16* __restrict__ lgh,
                                                   u16* __restrict__ am,
                                                   float* __restrict__ Wpq,
                                                   float* __restrict__ Wpk,
                                                   u16* __restrict__ WlT) {
    int bx = blockIdx.x;
    if (bx < 4096) {
        size_t g = ((size_t)bx * 256 + threadIdx.x) * 4;   // 4194304 total
        float4 a4 = *(const float4*)&Astat[g];
        int4 m4 = *(const int4*)&Mm[g];
        float a[4] = {a4.x, a4.y, a4.z, a4.w};
        int mm[4] = {m4.x, m4.y, m4.z, m4.w};
        ushort4 lo, ao;
        u16 lg[4], ab[4];
#pragma unroll
        for (int j = 0; j < 4; ++j) {
            float p = fminf(fmaxf(a[j], 1e-3f), 1.f - 1e-3f);
            float l = __logf(p / (1.f - p));          // ETA = 1.0
            lg[j] = mm[j] ? f2h(l) : (u16)0xFC00;     // -inf f16 when masked
            ab[j] = mm[j] ? f2bf(a[j]) : (u16)0;
        }
        lo.x = lg[0]; lo.y = lg[1]; lo.z = lg[2]; lo.w = lg[3];
        ao.x = ab[0]; ao.y = ab[1]; ao.z = ab[2]; ao.w = ab[3];
        *(ushort4*)&lgh[g] = lo;
        *(ushort4*)&am[g] = ao;
    } else if (bx == 4096) {
        for (int i = threadIdx.x; i < 8192; i += 256) {
            int d = i & 127;
            int c = (i >> 7) & 31;
            int mat = i >> 12;
            const float* Wt = mat ? Wk : Wq;
            float acc = 0.f;
#pragma unroll 4
            for (int e = 0; e < DD; ++e)
                acc = fmaf(Wproj[c * DD + e], Wt[e * DD + d], acc);
            (mat ? Wpk : Wpq)[c * DD + d] = acc;
        }
    } else {
        for (int i = threadIdx.x; i < 16384; i += 256) {
            int dp = i >> 7, d = i & 127;
            WlT[dp * DD + d] = f2bf(Wl[d * DD + dp]);
        }
    }
}

// ---------------- K3: fused pool + Hn/Q/K projections, emitted bf16 --------
__global__ __launch_bounds__(256) void proj3_kernel(const float* __restrict__ X,
                                                    const float* __restrict__ Msk,
                                                    const float* __restrict__ Wproj,
                                                    const float* __restrict__ Wpq,
                                                    const float* __restrict__ Wpk,
                                                    u16* __restrict__ HnT,
                                                    u16* __restrict__ Qb,
                                                    u16* __restrict__ Kb) {
    __shared__ float wp[CC * DD], wq[CC * DD], wk[CC * DD];
    __shared__ float xs[CC * 36];
    int t = threadIdx.x;
    for (int i = t; i < CC * DD; i += 256) {
        wp[i] = Wproj[i];
        wq[i] = Wpq[i];
        wk[i] = Wpk[i];
    }
    int rbase = blockIdx.x * 32;
    {   // masked temporal mean pooling: thread = (row, 4-col group)
        int row = t >> 3, cg = t & 7;
        const float* xrow = X + ((size_t)(rbase + row) * SS) * CC + cg * 4;
        const float* mrow = Msk + (size_t)(rbase + row) * SS;
        float4 acc = make_float4(0.f, 0.f, 0.f, 0.f);
        float msum = 0.f;
#pragma unroll
        for (int s = 0; s < SS; ++s) {
            float mv = mrow[s];
            float4 xv = *(const float4*)&xrow[s * CC];
            msum += mv;
            acc.x = fmaf(xv.x, mv, acc.x);
            acc.y = fmaf(xv.y, mv, acc.y);
            acc.z = fmaf(xv.z, mv, acc.z);
            acc.w = fmaf(xv.w, mv, acc.w);
        }
        float inv = 1.f / fmaxf(msum, 1.0f);
        xs[(cg * 4 + 0) * 36 + row] = acc.x * inv;
        xs[(cg * 4 + 1) * 36 + row] = acc.y * inv;
        xs[(cg * 4 + 2) * 36 + row] = acc.z * inv;
        xs[(cg * 4 + 3) * 36 + row] = acc.w * inv;
    }
    __syncthreads();

    int col = t & 127;
    int g = t >> 7;
    float ah[16], aq[16], ak[16];
#pragma unroll
    for (int i = 0; i < 16; ++i) { ah[i] = 0.f; aq[i] = 0.f; ak[i] = 0.f; }

#pragma unroll 4
    for (int k = 0; k < CC; ++k) {
        float wpv = wp[k * DD + col], wqv = wq[k * DD + col], wkv = wk[k * DD + col];
        const float4* xp = (const float4*)&xs[k * 36 + g * 16];
        float4 a0 = xp[0], a1 = xp[1], a2 = xp[2], a3 = xp[3];
        float xv[16] = {a0.x, a0.y, a0.z, a0.w, a1.x, a1.y, a1.z, a1.w,
                        a2.x, a2.y, a2.z, a2.w, a3.x, a3.y, a3.z, a3.w};
#pragma unroll
        for (int i = 0; i < 16; ++i) {
            ah[i] = fmaf(xv[i], wpv, ah[i]);
            aq[i] = fmaf(xv[i], wqv, aq[i]);
            ak[i] = fmaf(xv[i], wkv, ak[i]);
        }
    }
    const float scale = 0.08838834764831845f;     // 1/sqrt(128) folded into Q
#pragma unroll
    for (int i = 0; i < 16; ++i) {
        size_t row = (size_t)(rbase + g * 16 + i);
        Qb[row * DD + col] = f2bf(aq[i] * scale);
        Kb[row * DD + col] = f2bf(ak[i]);
    }
    int b = rbase >> 11;
    int n0 = (rbase & (NN - 1)) + g * 16;
    u16* hp = HnT + (size_t)b * DD * NN + (size_t)col * NN + n0;
    unsigned pk[8];
#pragma unroll
    for (int i = 0; i < 8; ++i)
        pk[i] = (unsigned)f2bf(ah[2 * i]) | ((unsigned)f2bf(ah[2 * i + 1]) << 16);
    *(uint4*)&hp[0] = make_uint4(pk[0], pk[1], pk[2], pk[3]);
    *(uint4*)&hp[8] = make_uint4(pk[4], pk[5], pk[6], pk[7]);
}

// ---------------- K4: stats — QK^T tile, e=exp(dot+lg) -> Ebuf, row partials
#define LQT 136
__global__ __launch_bounds__(256) void stats_kernel(
        const u16* __restrict__ Qb, const u16* __restrict__ Kb,
        const u16* __restrict__ lgh, const u16* __restrict__ am,
        const float* __restrict__ rel,
        u16* __restrict__ Ebuf, float* __restrict__ part) {
    __shared__ u16 Qs[32 * LQT];
    __shared__ u16 Ks[128 * LQT];
    __shared__ float redE[128], redR[128], redA[128];
    int cs = blockIdx.x, rt = blockIdx.y, b = blockIdx.z;
    int R0 = rt * 32, C0 = cs * 512;
    int t = threadIdx.x;
    int lane = t & 63, w = t >> 6, q = lane >> 4, r16 = lane & 15;

    const u16* Qg = Qb + ((size_t)b * NN + R0) * DD;
#pragma unroll
    for (int rep = 0; rep < 2; ++rep) {
        int e = rep * 256 + t;
        int row = e >> 4, seg = e & 15;
        *(uint4*)&Qs[row * LQT + seg * 8] = *(const uint4*)&Qg[row * DD + seg * 8];
    }
    const u16* Kg = Kb + (size_t)b * NN * DD;
    float ER[2][4], LR[2][4], LA[2][4];
#pragma unroll
    for (int i = 0; i < 2; ++i)
#pragma unroll
        for (int r = 0; r < 4; ++r) { ER[i][r] = 0.f; LR[i][r] = 0.f; LA[i][r] = 0.f; }

    for (int ct = 0; ct < 4; ++ct) {
        __syncthreads();
#pragma unroll
        for (int rep = 0; rep < 8; ++rep) {       // K tile: 128 cols x 128 k
            int e = rep * 256 + t;
            int colr = e >> 4, seg = e & 15;
            *(uint4*)&Ks[colr * LQT + seg * 8] =
                *(const uint4*)&Kg[(size_t)(C0 + ct * 128 + colr) * DD + seg * 8];
        }
        __syncthreads();
        f32x4 acc[2][2];
#pragma unroll
        for (int i = 0; i < 2; ++i)
#pragma unroll
            for (int j = 0; j < 2; ++j)
                acc[i][j] = (f32x4){0.f, 0.f, 0.f, 0.f};
#pragma unroll
        for (int ksp = 0; ksp < 4; ++ksp) {
            int ko = ksp * 32 + q * 8;
            bf16x8 a0 = *(const bf16x8*)&Qs[r16 * LQT + ko];
            bf16x8 a1 = *(const bf16x8*)&Qs[(16 + r16) * LQT + ko];
            bf16x8 b0 = *(const bf16x8*)&Ks[(w * 32 + r16) * LQT + ko];
            bf16x8 b1 = *(const bf16x8*)&Ks[(w * 32 + 16 + r16) * LQT + ko];
            acc[0][0] = __builtin_amdgcn_mfma_f32_16x16x32_bf16(a0, b0, acc[0][0], 0, 0, 0);
            acc[0][1] = __builtin_amdgcn_mfma_f32_16x16x32_bf16(a0, b1, acc[0][1], 0, 0, 0);
            acc[1][0] = __builtin_amdgcn_mfma_f32_16x16x32_bf16(a1, b0, acc[1][0], 0, 0, 0);
            acc[1][1] = __builtin_amdgcn_mfma_f32_16x16x32_bf16(a1, b1, acc[1][1], 0, 0, 0);
        }
        int m0 = C0 + ct * 128 + w * 32;
        float rm0 = clamp01(rel[b * NN + m0 + r16]);
        float rm1 = clamp01(rel[b * NN + m0 + 16 + r16]);
#pragma unroll
        for (int i = 0; i < 2; ++i)
#pragma unroll
            for (int r = 0; r < 4; ++r) {
                int n = R0 + i * 16 + q * 4 + r;
                const u16* lrow = lgh + (size_t)n * NN + m0;
                const u16* arow = am + (size_t)n * NN + m0;
                float lg0 = h2f(lrow[r16]), lg1 = h2f(lrow[16 + r16]);
                float a0 = bf2f(arow[r16]), a1 = bf2f(arow[16 + r16]);
                u16 eb0 = f2bf(__expf(acc[i][0][r] + lg0));   // masked: -inf -> 0
                u16 eb1 = f2bf(__expf(acc[i][1][r] + lg1));
                size_t o = ((size_t)b * NN + n) * NN + m0;
                Ebuf[o + r16] = eb0;
                Ebuf[o + 16 + r16] = eb1;
                float e0 = bf2f(eb0), e1 = bf2f(eb1);         // sum the ROUNDED e
                ER[i][r] += e0 + e1;
                LR[i][r] = fmaf(e0, rm0, fmaf(e1, rm1, LR[i][r]));
                LA[i][r] = fmaf(a0, rm0, fmaf(a1, rm1, LA[i][r]));
            }
    }
#pragma unroll
    for (int i = 0; i < 2; ++i)
#pragma unroll
        for (int r = 0; r < 4; ++r) {
            float e = ER[i][r], lr = LR[i][r], la = LA[i][r];
#pragma unroll
            for (int off = 1; off < 16; off <<= 1) {
                e += __shfl_xor(e, off);
                lr += __shfl_xor(lr, off);
                la += __shfl_xor(la, off);
            }
            if (r16 == 0) {
                int row = i * 16 + q * 4 + r;
                redE[w * 32 + row] = e;
                redR[w * 32 + row] = lr;
                redA[w * 32 + row] = la;
            }
        }
    __syncthreads();
    if (t < 32) {
        float es = redE[t] + redE[32 + t] + redE[64 + t] + redE[96 + t];
        float lr = redR[t] + redR[32 + t] + redR[64 + t] + redR[96 + t];
        float la = redA[t] + redA[32 + t] + redA[64 + t] + redA[96 + t];
        float* p = part + ((size_t)((b * 64 + rt) * 4 + cs)) * 96;
        p[t] = es;
        p[32 + t] = lr;
        p[64 + t] = la;
    }
}

// ---------------- K5: full-K GEMM1 (512 thr, pipelined) + fused tail -------
// 8 waves: wave w covers rows (w>>2)*16..+16, cols (w&3)*32..+32 of 32x128 H.
// Register-pipelined A/B staging: next K-step's global loads are issued
// before the MFMA barrier so HBM latency hides under MFMA (T14).
#define LPT 72
#define LWT 136
__global__ __launch_bounds__(512) void prop_kernel(
        const u16* __restrict__ Ebuf, const u16* __restrict__ am,
        const float* __restrict__ part, const float* __restrict__ rel,
        const u16* __restrict__ HnT, const u16* __restrict__ WlT,
        const float* __restrict__ s1, const float* __restrict__ b1,
        const float* __restrict__ s2, const float* __restrict__ b2,
        float* __restrict__ Af, float* __restrict__ out) {
    __shared__ union {
        struct { u16 As[32 * LPT]; u16 Bs[128 * LPT]; } ab;       // 23040 B
        struct { u16 Ws[128 * LWT]; u16 Hs[32 * LWT]; } fin;      // 43520 B
    } sm;
    __shared__ float redS[128], redQ[128];
    __shared__ float2 MV[32];
    __shared__ float2 cfs[32];
    int rt = blockIdx.x, b = blockIdx.y;
    int R0 = rt * 32;
    int t = threadIdx.x;
    int lane = t & 63, w = t >> 6, q = lane >> 4, r16 = lane & 15;
    int wr = (w >> 2) * 16;           // wave row base
    int wc = (w & 3) * 32;            // wave col base

    // ---- fused coef ----
    if (t < 32) {
        const float* p = part + ((size_t)((b * 64 + rt) * 4)) * 96;
        float es = 0.f, lr = 0.f, la = 0.f;
#pragma unroll
        for (int cs = 0; cs < 4; ++cs) {
            es += p[cs * 96 + t];
            lr += p[cs * 96 + 32 + t];
            la += p[cs * 96 + 64 + t];
        }
        float rn = clamp01(rel[b * NN + R0 + t]);
        float inv = 1.f / es;                     // es > 0 (diag edge kept)
        float fsum = rn * (0.6f * lr * inv + 0.4f * la);
        float nrm = 1.f / (fsum + 1e-8f);
        cfs[t] = make_float2(0.6f * inv * rn * nrm, 0.4f * rn * nrm);
    }
    __syncthreads();

    // A-side: thread handles row arow, 4 cols at ac within each 64-chunk
    int arow = t >> 4, ac = (t & 15) * 4;
    float2 cf = cfs[arow];
    const u16* Eg = Ebuf + ((size_t)b * NN + R0 + arow) * NN;
    const u16* ag = am + (size_t)(R0 + arow) * NN;
    const float* rg = rel + b * NN;
    const u16* Bg = HnT + (size_t)b * DD * NN;
    float* Afg = Af + ((size_t)b * NN + R0 + arow) * NN;

    // B-side: 1024 (d,seg) slots over 2 reps of 512 threads
    int bd0 = t >> 3, bs0 = (t & 7) * 8;
    int bd1 = (512 + t) >> 3, bs1 = bs0;

    f32x4 acc[2];
    acc[0] = (f32x4){0.f, 0.f, 0.f, 0.f};
    acc[1] = (f32x4){0.f, 0.f, 0.f, 0.f};

    // prologue: prefetch kc=0
    uint2 pe = *(const uint2*)&Eg[ac];
    uint2 pa = *(const uint2*)&ag[ac];
    float4 pr = *(const float4*)&rg[ac];
    uint4 pb0 = *(const uint4*)&Bg[(size_t)bd0 * NN + bs0];
    uint4 pb1 = *(const uint4*)&Bg[(size_t)bd1 * NN + bs1];

    for (int kc = 0; kc < NN; kc += 64) {
        __syncthreads();            // prev MFMA done reading LDS
        {   // consume A regs: A_fuse materialize + bf16 pack to LDS
            float e0 = bf2f((u16)(pe.x & 0xffff)), e1 = bf2f((u16)(pe.x >> 16));
            float e2 = bf2f((u16)(pe.y & 0xffff)), e3 = bf2f((u16)(pe.y >> 16));
            float a0 = bf2f((u16)(pa.x & 0xffff)), a1 = bf2f((u16)(pa.x >> 16));
            float a2 = bf2f((u16)(pa.y & 0xffff)), a3 = bf2f((u16)(pa.y >> 16));
            float r0 = clamp01(pr.x), r1 = clamp01(pr.y);
            float r2 = clamp01(pr.z), r3 = clamp01(pr.w);
            float v0 = r0 * fmaf(e0, cf.x, a0 * cf.y);
            float v1 = r1 * fmaf(e1, cf.x, a1 * cf.y);
            float v2 = r2 * fmaf(e2, cf.x, a2 * cf.y);
            float v3 = r3 * fmaf(e3, cf.x, a3 * cf.y);
            *(float4*)&Afg[kc + ac] = make_float4(v0, v1, v2, v3);
            unsigned pk0 = (unsigned)f2bf(v0) | ((unsigned)f2bf(v1) << 16);
            unsigned pk1 = (unsigned)f2bf(v2) | ((unsigned)f2bf(v3) << 16);
            *(uint2*)&sm.ab.As[arow * LPT + ac] = make_uint2(pk0, pk1);
        }
        *(uint4*)&sm.ab.Bs[bd0 * LPT + bs0] = pb0;
        *(uint4*)&sm.ab.Bs[bd1 * LPT + bs1] = pb1;
        if (kc + 64 < NN) {         // prefetch next chunk (hidden under MFMA)
            int kn = kc + 64;
            pe = *(const uint2*)&Eg[kn + ac];
            pa = *(const uint2*)&ag[kn + ac];
            pr = *(const float4*)&rg[kn + ac];
            pb0 = *(const uint4*)&Bg[(size_t)bd0 * NN + kn + bs0];
            pb1 = *(const uint4*)&Bg[(size_t)bd1 * NN + kn + bs1];
        }
        __syncthreads();
#pragma unroll
        for (int kst = 0; kst < 2; ++kst) {
            int ko = kst * 32 + q * 8;
            bf16x8 a0 = *(const bf16x8*)&sm.ab.As[(wr + r16) * LPT + ko];
            bf16x8 b0 = *(const bf16x8*)&sm.ab.Bs[(wc + r16) * LPT + ko];
            bf16x8 b1v = *(const bf16x8*)&sm.ab.Bs[(wc + 16 + r16) * LPT + ko];
            acc[0] = __builtin_amdgcn_mfma_f32_16x16x32_bf16(a0, b0, acc[0], 0, 0, 0);
            acc[1] = __builtin_amdgcn_mfma_f32_16x16x32_bf16(a0, b1v, acc[1], 0, 0, 0);
        }
    }

    // ---- fused final: H -> bf16 LDS, @W_lin, relu, LN1, LN2 ----
    __syncthreads();                // all MFMA reads done before union reuse
#pragma unroll
    for (int rep = 0; rep < 4; ++rep) {
        int e = rep * 512 + t;      // 2048 uint4 slots
        int dp = e >> 4, seg = e & 15;
        *(uint4*)&sm.fin.Ws[dp * LWT + seg * 8] = *(const uint4*)&WlT[dp * DD + seg * 8];
    }
#pragma unroll
    for (int j = 0; j < 2; ++j)
#pragma unroll
        for (int r = 0; r < 4; ++r)
            sm.fin.Hs[(wr + q * 4 + r) * LWT + wc + j * 16 + r16] = f2bf(acc[j][r]);
    __syncthreads();

    f32x4 c2[2];
    c2[0] = (f32x4){0.f, 0.f, 0.f, 0.f};
    c2[1] = (f32x4){0.f, 0.f, 0.f, 0.f};
#pragma unroll
    for (int ksp = 0; ksp < 4; ++ksp) {
        int ko = ksp * 32 + q * 8;
        bf16x8 a0 = *(const bf16x8*)&sm.fin.Hs[(wr + r16) * LWT + ko];
        bf16x8 b0 = *(const bf16x8*)&sm.fin.Ws[(wc + r16) * LWT + ko];
        bf16x8 b1v = *(const bf16x8*)&sm.fin.Ws[(wc + 16 + r16) * LWT + ko];
        c2[0] = __builtin_amdgcn_mfma_f32_16x16x32_bf16(a0, b0, c2[0], 0, 0, 0);
        c2[1] = __builtin_amdgcn_mfma_f32_16x16x32_bf16(a0, b1v, c2[1], 0, 0, 0);
    }
    float v[2][4];
#pragma unroll
    for (int j = 0; j < 2; ++j)
#pragma unroll
        for (int r = 0; r < 4; ++r)
            v[j][r] = fmaxf(c2[j][r], 0.f);

    int c0 = wc + r16, c1 = wc + 16 + r16;
    float s1c0 = s1[c0], s1c1 = s1[c1], b1c0 = b1[c0], b1c1 = b1[c1];
    float s2c0 = s2[c0], s2c1 = s2[c1], b2c0 = b2[c0], b2c1 = b2[c1];
    int g4 = (w & 3) * 32;          // reduction group offset

#pragma unroll
    for (int r = 0; r < 4; ++r) {
        float s = v[0][r] + v[1][r];
        float qq = v[0][r] * v[0][r] + v[1][r] * v[1][r];
#pragma unroll
        for (int off = 1; off < 16; off <<= 1) {
            s += __shfl_xor(s, off);
            qq += __shfl_xor(qq, off);
        }
        if (r16 == 0) {
            int row = wr + q * 4 + r;
            redS[g4 + row] = s;
            redQ[g4 + row] = qq;
        }
    }
    __syncthreads();
    if (t < 32) {
        float s = redS[t] + redS[32 + t] + redS[64 + t] + redS[96 + t];
        float qq = redQ[t] + redQ[32 + t] + redQ[64 + t] + redQ[96 + t];
        float mu = s * (1.f / 128.f);
        float var = qq * (1.f / 128.f) - mu * mu;
        MV[t] = make_float2(mu, 1.f / sqrtf(var + 1e-5f));
    }
    __syncthreads();
    float y[2][4];
#pragma unroll
    for (int r = 0; r < 4; ++r) {
        float2 mv = MV[wr + q * 4 + r];
        y[0][r] = (v[0][r] - mv.x) * mv.y * s1c0 + b1c0;
        y[1][r] = (v[1][r] - mv.x) * mv.y * s1c1 + b1c1;
    }
    __syncthreads();
#pragma unroll
    for (int r = 0; r < 4; ++r) {
        float s = y[0][r] + y[1][r];
        float qq = y[0][r] * y[0][r] + y[1][r] * y[1][r];
#pragma unroll
        for (int off = 1; off < 16; off <<= 1) {
            s += __shfl_xor(s, off);
            qq += __shfl_xor(qq, off);
        }
        if (r16 == 0) {
            int row = wr + q * 4 + r;
            redS[g4 + row] = s;
            redQ[g4 + row] = qq;
        }
    }
    __syncthreads();
    if (t < 32) {
        float s = redS[t] + redS[32 + t] + redS[64 + t] + redS[96 + t];
        float qq = redQ[t] + redQ[32 + t] + redQ[64 + t] + redQ[96 + t];
        float mu = s * (1.f / 128.f);
        float var = qq * (1.f / 128.f) - mu * mu;
        MV[t] = make_float2(mu, 1.f / sqrtf(var + 1e-5f));
    }
    __syncthreads();
#pragma unroll
    for (int r = 0; r < 4; ++r) {
        float2 mv = MV[wr + q * 4 + r];
        size_t o = ((size_t)b * NN + R0 + wr + q * 4 + r) * DD;
        out[o + c0] = (y[0][r] - mv.x) * mv.y * s2c0 + b2c0;
        out[o + c1] = (y[1][r] - mv.x) * mv.y * s2c1 + b2c1;
    }
}

extern "C" void kernel_launch(void* const* d_in, const int* in_sizes, int n_in,
                              void* d_out, int out_size, void* d_ws, size_t ws_size,
                              hipStream_t stream) {
    const float* X = (const float*)d_in[0];
    const float* Msk = (const float*)d_in[1];
    const float* Astat = (const float*)d_in[2];
    const int* Mm = (const int*)d_in[3];
    const float* rel = (const float*)d_in[4];
    const float* Wproj = (const float*)d_in[5];
    const float* Wq = (const float*)d_in[6];
    const float* Wk = (const float*)d_in[7];
    const float* Wlin = (const float*)d_in[8];
    const float* s1 = (const float*)d_in[9];
    const float* b1 = (const float*)d_in[10];
    const float* s2 = (const float*)d_in[11];
    const float* b2 = (const float*)d_in[12];

    float* outMain = (float*)d_out;                       // (B,N,D)
    float* Afuse = outMain + (size_t)BB * NN * DD;        // (B,N,N)

    float* w_ = (float*)d_ws;
    float* Wpq = w_;                                      // 4096 f
    float* Wpk = w_ + 4096;                               // 4096 f
    u16* WlT = (u16*)(w_ + 8192);                         // 16384 u16
    u16* Qb = (u16*)(w_ + 16384);                         // 2097152 u16
    u16* Kb = (u16*)(w_ + 1064960);                       // 2097152 u16
    u16* HnT = (u16*)(w_ + 2113536);                      // 2097152 u16
    u16* lgh = (u16*)(w_ + 3162112);                      // 4194304 u16 (f16)
    u16* am = (u16*)(w_ + 5259264);                       // 4194304 u16 (bf16)
    u16* Ebuf = (u16*)(w_ + 7356416);                     // 33554432 u16 (bf16)
    float* part = w_ + 24133632;                          // 196608 f

    prep_kernel<<<dim3(4098), dim3(256), 0, stream>>>(
        Astat, Mm, Wproj, Wq, Wk, Wlin, lgh, am, Wpq, Wpk, WlT);
    proj3_kernel<<<dim3(512), dim3(256), 0, stream>>>(X, Msk, Wproj, Wpq, Wpk, HnT, Qb, Kb);

    stats_kernel<<<dim3(4, 64, 8), dim3(256), 0, stream>>>(
        Qb, Kb, lgh, am, rel, Ebuf, part);
    prop_kernel<<<dim3(64, 8), dim3(512), 0, stream>>>(
        Ebuf, am, part, rel, HnT, WlT, s1, b1, s2, b2, Afuse, outMain);
}

// Round 3
// 353.057 us; speedup vs baseline: 1.3870x; 1.3870x over previous
//
#include <hip/hip_runtime.h>
#include <math.h>

#define BB 8
#define NN 2048
#define SS 16
#define CC 32
#define DD 128

typedef unsigned short u16;
typedef __attribute__((ext_vector_type(8))) short bf16x8;
typedef __attribute__((ext_vector_type(4))) float f32x4;

__device__ inline u16 f2bf(float f) {
    union { float f; unsigned u; } c; c.f = f;
    unsigned r = c.u + 0x7fff + ((c.u >> 16) & 1);   // round-to-nearest-even
    return (u16)(r >> 16);
}
__device__ inline float bf2f(u16 h) {
    union { unsigned u; float f; } c; c.u = ((unsigned)h) << 16;
    return c.f;
}
__device__ inline u16 f2h(float f) {
    union { _Float16 h; u16 u; } c; c.h = (_Float16)f;
    return c.u;
}
__device__ inline float h2f(u16 u) {
    union { _Float16 h; u16 v; } c; c.v = u;
    return (float)c.h;
}
__device__ inline float clamp01(float v) { return fminf(fmaxf(v, 0.f), 1.f); }

// ---------------- K1: merged prep: bias tables + wcomb + wlt ---------------
// blocks 0..4095   : bias_prep (lgh f16 -inf-masked, am bf16)
// blocks 4096..4127: Wpq = Wproj@Wq, Wpk = Wproj@Wk (one output/thread)
// blocks 4128..4191: WlT = bf16(Wlin^T) (one output/thread)
__global__ __launch_bounds__(256) void prep_kernel(const float* __restrict__ Astat,
                                                   const int* __restrict__ Mm,
                                                   const float* __restrict__ Wproj,
                                                   const float* __restrict__ Wq,
                                                   const float* __restrict__ Wk,
                                                   const float* __restrict__ Wl,
                                                   u16* __restrict__ lgh,
                                                   u16* __restrict__ am,
                                                   float* __restrict__ Wpq,
                                                   float* __restrict__ Wpk,
                                                   u16* __restrict__ WlT) {
    int bx = blockIdx.x;
    if (bx < 4096) {
        size_t g = ((size_t)bx * 256 + threadIdx.x) * 4;   // 4194304 total
        float4 a4 = *(const float4*)&Astat[g];
        int4 m4 = *(const int4*)&Mm[g];
        float a[4] = {a4.x, a4.y, a4.z, a4.w};
        int mm[4] = {m4.x, m4.y, m4.z, m4.w};
        ushort4 lo, ao;
        u16 lg[4], ab[4];
#pragma unroll
        for (int j = 0; j < 4; ++j) {
            float p = fminf(fmaxf(a[j], 1e-3f), 1.f - 1e-3f);
            float l = __logf(p / (1.f - p));          // ETA = 1.0
            lg[j] = mm[j] ? f2h(l) : (u16)0xFC00;     // -inf f16 when masked
            ab[j] = mm[j] ? f2bf(a[j]) : (u16)0;
        }
        lo.x = lg[0]; lo.y = lg[1]; lo.z = lg[2]; lo.w = lg[3];
        ao.x = ab[0]; ao.y = ab[1]; ao.z = ab[2]; ao.w = ab[3];
        *(ushort4*)&lgh[g] = lo;
        *(ushort4*)&am[g] = ao;
    } else if (bx < 4128) {
        int i = (bx - 4096) * 256 + threadIdx.x;      // 8192 outputs
        int d = i & 127;
        int c = (i >> 7) & 31;
        int mat = i >> 12;
        const float* Wt = mat ? Wk : Wq;
        float acc = 0.f;
#pragma unroll 4
        for (int e = 0; e < DD; ++e)
            acc = fmaf(Wproj[c * DD + e], Wt[e * DD + d], acc);
        (mat ? Wpk : Wpq)[c * DD + d] = acc;
    } else {
        int i = (bx - 4128) * 256 + threadIdx.x;      // 16384 outputs
        int dp = i >> 7, d = i & 127;
        WlT[dp * DD + d] = f2bf(Wl[d * DD + dp]);
    }
}

// ---------------- K3: fused pool + Hn/Q/K projections, emitted bf16 --------
__global__ __launch_bounds__(256) void proj3_kernel(const float* __restrict__ X,
                                                    const float* __restrict__ Msk,
                                                    const float* __restrict__ Wproj,
                                                    const float* __restrict__ Wpq,
                                                    const float* __restrict__ Wpk,
                                                    u16* __restrict__ HnT,
                                                    u16* __restrict__ Qb,
                                                    u16* __restrict__ Kb) {
    __shared__ float wp[CC * DD], wq[CC * DD], wk[CC * DD];
    __shared__ float xs[CC * 36];
    int t = threadIdx.x;
    for (int i = t; i < CC * DD; i += 256) {
        wp[i] = Wproj[i];
        wq[i] = Wpq[i];
        wk[i] = Wpk[i];
    }
    int rbase = blockIdx.x * 32;
    {   // masked temporal mean pooling: thread = (row, 4-col group)
        int row = t >> 3, cg = t & 7;
        const float* xrow = X + ((size_t)(rbase + row) * SS) * CC + cg * 4;
        const float* mrow = Msk + (size_t)(rbase + row) * SS;
        float4 acc = make_float4(0.f, 0.f, 0.f, 0.f);
        float msum = 0.f;
#pragma unroll
        for (int s = 0; s < SS; ++s) {
            float mv = mrow[s];
            float4 xv = *(const float4*)&xrow[s * CC];
            msum += mv;
            acc.x = fmaf(xv.x, mv, acc.x);
            acc.y = fmaf(xv.y, mv, acc.y);
            acc.z = fmaf(xv.z, mv, acc.z);
            acc.w = fmaf(xv.w, mv, acc.w);
        }
        float inv = 1.f / fmaxf(msum, 1.0f);
        xs[(cg * 4 + 0) * 36 + row] = acc.x * inv;
        xs[(cg * 4 + 1) * 36 + row] = acc.y * inv;
        xs[(cg * 4 + 2) * 36 + row] = acc.z * inv;
        xs[(cg * 4 + 3) * 36 + row] = acc.w * inv;
    }
    __syncthreads();

    int col = t & 127;
    int g = t >> 7;
    float ah[16], aq[16], ak[16];
#pragma unroll
    for (int i = 0; i < 16; ++i) { ah[i] = 0.f; aq[i] = 0.f; ak[i] = 0.f; }

#pragma unroll 4
    for (int k = 0; k < CC; ++k) {
        float wpv = wp[k * DD + col], wqv = wq[k * DD + col], wkv = wk[k * DD + col];
        const float4* xp = (const float4*)&xs[k * 36 + g * 16];
        float4 a0 = xp[0], a1 = xp[1], a2 = xp[2], a3 = xp[3];
        float xv[16] = {a0.x, a0.y, a0.z, a0.w, a1.x, a1.y, a1.z, a1.w,
                        a2.x, a2.y, a2.z, a2.w, a3.x, a3.y, a3.z, a3.w};
#pragma unroll
        for (int i = 0; i < 16; ++i) {
            ah[i] = fmaf(xv[i], wpv, ah[i]);
            aq[i] = fmaf(xv[i], wqv, aq[i]);
            ak[i] = fmaf(xv[i], wkv, ak[i]);
        }
    }
    const float scale = 0.08838834764831845f;     // 1/sqrt(128) folded into Q
#pragma unroll
    for (int i = 0; i < 16; ++i) {
        size_t row = (size_t)(rbase + g * 16 + i);
        Qb[row * DD + col] = f2bf(aq[i] * scale);
        Kb[row * DD + col] = f2bf(ak[i]);
    }
    int b = rbase >> 11;
    int n0 = (rbase & (NN - 1)) + g * 16;
    u16* hp = HnT + (size_t)b * DD * NN + (size_t)col * NN + n0;
    unsigned pk[8];
#pragma unroll
    for (int i = 0; i < 8; ++i)
        pk[i] = (unsigned)f2bf(ah[2 * i]) | ((unsigned)f2bf(ah[2 * i + 1]) << 16);
    *(uint4*)&hp[0] = make_uint4(pk[0], pk[1], pk[2], pk[3]);
    *(uint4*)&hp[8] = make_uint4(pk[4], pk[5], pk[6], pk[7]);
}

// ---------------- K4: stats — QK^T tile, e=exp(dot+lg) -> Ebuf, row partials
#define LQT 136
__global__ __launch_bounds__(256) void stats_kernel(
        const u16* __restrict__ Qb, const u16* __restrict__ Kb,
        const u16* __restrict__ lgh, const u16* __restrict__ am,
        const float* __restrict__ rel,
        u16* __restrict__ Ebuf, float* __restrict__ part) {
    __shared__ u16 Qs[32 * LQT];
    __shared__ u16 Ks[128 * LQT];
    __shared__ float redE[128], redR[128], redA[128];
    int cs = blockIdx.x, rt = blockIdx.y, b = blockIdx.z;
    int R0 = rt * 32, C0 = cs * 512;
    int t = threadIdx.x;
    int lane = t & 63, w = t >> 6, q = lane >> 4, r16 = lane & 15;

    const u16* Qg = Qb + ((size_t)b * NN + R0) * DD;
#pragma unroll
    for (int rep = 0; rep < 2; ++rep) {
        int e = rep * 256 + t;
        int row = e >> 4, seg = e & 15;
        *(uint4*)&Qs[row * LQT + seg * 8] = *(const uint4*)&Qg[row * DD + seg * 8];
    }
    const u16* Kg = Kb + (size_t)b * NN * DD;
    float ER[2][4], LR[2][4], LA[2][4];
#pragma unroll
    for (int i = 0; i < 2; ++i)
#pragma unroll
        for (int r = 0; r < 4; ++r) { ER[i][r] = 0.f; LR[i][r] = 0.f; LA[i][r] = 0.f; }

    for (int ct = 0; ct < 4; ++ct) {
        __syncthreads();
#pragma unroll
        for (int rep = 0; rep < 8; ++rep) {       // K tile: 128 cols x 128 k
            int e = rep * 256 + t;
            int colr = e >> 4, seg = e & 15;
            *(uint4*)&Ks[colr * LQT + seg * 8] =
                *(const uint4*)&Kg[(size_t)(C0 + ct * 128 + colr) * DD + seg * 8];
        }
        __syncthreads();
        f32x4 acc[2][2];
#pragma unroll
        for (int i = 0; i < 2; ++i)
#pragma unroll
            for (int j = 0; j < 2; ++j)
                acc[i][j] = (f32x4){0.f, 0.f, 0.f, 0.f};
#pragma unroll
        for (int ksp = 0; ksp < 4; ++ksp) {
            int ko = ksp * 32 + q * 8;
            bf16x8 a0 = *(const bf16x8*)&Qs[r16 * LQT + ko];
            bf16x8 a1 = *(const bf16x8*)&Qs[(16 + r16) * LQT + ko];
            bf16x8 b0 = *(const bf16x8*)&Ks[(w * 32 + r16) * LQT + ko];
            bf16x8 b1 = *(const bf16x8*)&Ks[(w * 32 + 16 + r16) * LQT + ko];
            acc[0][0] = __builtin_amdgcn_mfma_f32_16x16x32_bf16(a0, b0, acc[0][0], 0, 0, 0);
            acc[0][1] = __builtin_amdgcn_mfma_f32_16x16x32_bf16(a0, b1, acc[0][1], 0, 0, 0);
            acc[1][0] = __builtin_amdgcn_mfma_f32_16x16x32_bf16(a1, b0, acc[1][0], 0, 0, 0);
            acc[1][1] = __builtin_amdgcn_mfma_f32_16x16x32_bf16(a1, b1, acc[1][1], 0, 0, 0);
        }
        int m0 = C0 + ct * 128 + w * 32;
        float rm0 = clamp01(rel[b * NN + m0 + r16]);
        float rm1 = clamp01(rel[b * NN + m0 + 16 + r16]);
#pragma unroll
        for (int i = 0; i < 2; ++i)
#pragma unroll
            for (int r = 0; r < 4; ++r) {
                int n = R0 + i * 16 + q * 4 + r;
                const u16* lrow = lgh + (size_t)n * NN + m0;
                const u16* arow = am + (size_t)n * NN + m0;
                float lg0 = h2f(lrow[r16]), lg1 = h2f(lrow[16 + r16]);
                float a0 = bf2f(arow[r16]), a1 = bf2f(arow[16 + r16]);
                u16 eb0 = f2bf(__expf(acc[i][0][r] + lg0));   // masked: -inf -> 0
                u16 eb1 = f2bf(__expf(acc[i][1][r] + lg1));
                size_t o = ((size_t)b * NN + n) * NN + m0;
                Ebuf[o + r16] = eb0;
                Ebuf[o + 16 + r16] = eb1;
                float e0 = bf2f(eb0), e1 = bf2f(eb1);         // sum the ROUNDED e
                ER[i][r] += e0 + e1;
                LR[i][r] = fmaf(e0, rm0, fmaf(e1, rm1, LR[i][r]));
                LA[i][r] = fmaf(a0, rm0, fmaf(a1, rm1, LA[i][r]));
            }
    }
#pragma unroll
    for (int i = 0; i < 2; ++i)
#pragma unroll
        for (int r = 0; r < 4; ++r) {
            float e = ER[i][r], lr = LR[i][r], la = LA[i][r];
#pragma unroll
            for (int off = 1; off < 16; off <<= 1) {
                e += __shfl_xor(e, off);
                lr += __shfl_xor(lr, off);
                la += __shfl_xor(la, off);
            }
            if (r16 == 0) {
                int row = i * 16 + q * 4 + r;
                redE[w * 32 + row] = e;
                redR[w * 32 + row] = lr;
                redA[w * 32 + row] = la;
            }
        }
    __syncthreads();
    if (t < 32) {
        float es = redE[t] + redE[32 + t] + redE[64 + t] + redE[96 + t];
        float lr = redR[t] + redR[32 + t] + redR[64 + t] + redR[96 + t];
        float la = redA[t] + redA[32 + t] + redA[64 + t] + redA[96 + t];
        float* p = part + ((size_t)((b * 64 + rt) * 4 + cs)) * 96;
        p[t] = es;
        p[32 + t] = lr;
        p[64 + t] = la;
    }
}

// ---------------- K5: full-K GEMM1 (512 thr, pipelined) + fused tail -------
#define LPT 72
#define LWT 136
__global__ __launch_bounds__(512) void prop_kernel(
        const u16* __restrict__ Ebuf, const u16* __restrict__ am,
        const float* __restrict__ part, const float* __restrict__ rel,
        const u16* __restrict__ HnT, const u16* __restrict__ WlT,
        const float* __restrict__ s1, const float* __restrict__ b1,
        const float* __restrict__ s2, const float* __restrict__ b2,
        float* __restrict__ Af, float* __restrict__ out) {
    __shared__ union {
        struct { u16 As[32 * LPT]; u16 Bs[128 * LPT]; } ab;       // 23040 B
        struct { u16 Ws[128 * LWT]; u16 Hs[32 * LWT]; } fin;      // 43520 B
    } sm;
    __shared__ float redS[128], redQ[128];
    __shared__ float2 MV[32];
    __shared__ float2 cfs[32];
    int rt = blockIdx.x, b = blockIdx.y;
    int R0 = rt * 32;
    int t = threadIdx.x;
    int lane = t & 63, w = t >> 6, q = lane >> 4, r16 = lane & 15;
    int wr = (w >> 2) * 16;           // wave row base
    int wc = (w & 3) * 32;            // wave col base

    // ---- fused coef ----
    if (t < 32) {
        const float* p = part + ((size_t)((b * 64 + rt) * 4)) * 96;
        float es = 0.f, lr = 0.f, la = 0.f;
#pragma unroll
        for (int cs = 0; cs < 4; ++cs) {
            es += p[cs * 96 + t];
            lr += p[cs * 96 + 32 + t];
            la += p[cs * 96 + 64 + t];
        }
        float rn = clamp01(rel[b * NN + R0 + t]);
        float inv = 1.f / es;                     // es > 0 (diag edge kept)
        float fsum = rn * (0.6f * lr * inv + 0.4f * la);
        float nrm = 1.f / (fsum + 1e-8f);
        cfs[t] = make_float2(0.6f * inv * rn * nrm, 0.4f * rn * nrm);
    }
    __syncthreads();

    // A-side: thread handles row arow, 4 cols at ac within each 64-chunk
    int arow = t >> 4, ac = (t & 15) * 4;
    float2 cf = cfs[arow];
    const u16* Eg = Ebuf + ((size_t)b * NN + R0 + arow) * NN;
    const u16* ag = am + (size_t)(R0 + arow) * NN;
    const float* rg = rel + b * NN;
    const u16* Bg = HnT + (size_t)b * DD * NN;
    float* Afg = Af + ((size_t)b * NN + R0 + arow) * NN;

    // B-side: 1024 (d,seg) slots over 2 reps of 512 threads
    int bd0 = t >> 3, bs0 = (t & 7) * 8;
    int bd1 = (512 + t) >> 3, bs1 = bs0;

    f32x4 acc[2];
    acc[0] = (f32x4){0.f, 0.f, 0.f, 0.f};
    acc[1] = (f32x4){0.f, 0.f, 0.f, 0.f};

    // prologue: prefetch kc=0
    uint2 pe = *(const uint2*)&Eg[ac];
    uint2 pa = *(const uint2*)&ag[ac];
    float4 pr = *(const float4*)&rg[ac];
    uint4 pb0 = *(const uint4*)&Bg[(size_t)bd0 * NN + bs0];
    uint4 pb1 = *(const uint4*)&Bg[(size_t)bd1 * NN + bs1];

    for (int kc = 0; kc < NN; kc += 64) {
        __syncthreads();            // prev MFMA done reading LDS
        {   // consume A regs: A_fuse materialize + bf16 pack to LDS
            float e0 = bf2f((u16)(pe.x & 0xffff)), e1 = bf2f((u16)(pe.x >> 16));
            float e2 = bf2f((u16)(pe.y & 0xffff)), e3 = bf2f((u16)(pe.y >> 16));
            float a0 = bf2f((u16)(pa.x & 0xffff)), a1 = bf2f((u16)(pa.x >> 16));
            float a2 = bf2f((u16)(pa.y & 0xffff)), a3 = bf2f((u16)(pa.y >> 16));
            float r0 = clamp01(pr.x), r1 = clamp01(pr.y);
            float r2 = clamp01(pr.z), r3 = clamp01(pr.w);
            float v0 = r0 * fmaf(e0, cf.x, a0 * cf.y);
            float v1 = r1 * fmaf(e1, cf.x, a1 * cf.y);
            float v2 = r2 * fmaf(e2, cf.x, a2 * cf.y);
            float v3 = r3 * fmaf(e3, cf.x, a3 * cf.y);
            *(float4*)&Afg[kc + ac] = make_float4(v0, v1, v2, v3);
            unsigned pk0 = (unsigned)f2bf(v0) | ((unsigned)f2bf(v1) << 16);
            unsigned pk1 = (unsigned)f2bf(v2) | ((unsigned)f2bf(v3) << 16);
            *(uint2*)&sm.ab.As[arow * LPT + ac] = make_uint2(pk0, pk1);
        }
        *(uint4*)&sm.ab.Bs[bd0 * LPT + bs0] = pb0;
        *(uint4*)&sm.ab.Bs[bd1 * LPT + bs1] = pb1;
        if (kc + 64 < NN) {         // prefetch next chunk (hidden under MFMA)
            int kn = kc + 64;
            pe = *(const uint2*)&Eg[kn + ac];
            pa = *(const uint2*)&ag[kn + ac];
            pr = *(const float4*)&rg[kn + ac];
            pb0 = *(const uint4*)&Bg[(size_t)bd0 * NN + kn + bs0];
            pb1 = *(const uint4*)&Bg[(size_t)bd1 * NN + kn + bs1];
        }
        __syncthreads();
#pragma unroll
        for (int kst = 0; kst < 2; ++kst) {
            int ko = kst * 32 + q * 8;
            bf16x8 a0 = *(const bf16x8*)&sm.ab.As[(wr + r16) * LPT + ko];
            bf16x8 b0 = *(const bf16x8*)&sm.ab.Bs[(wc + r16) * LPT + ko];
            bf16x8 b1v = *(const bf16x8*)&sm.ab.Bs[(wc + 16 + r16) * LPT + ko];
            acc[0] = __builtin_amdgcn_mfma_f32_16x16x32_bf16(a0, b0, acc[0], 0, 0, 0);
            acc[1] = __builtin_amdgcn_mfma_f32_16x16x32_bf16(a0, b1v, acc[1], 0, 0, 0);
        }
    }

    // ---- fused final: H -> bf16 LDS, @W_lin, relu, LN1, LN2 ----
    __syncthreads();                // all MFMA reads done before union reuse
#pragma unroll
    for (int rep = 0; rep < 4; ++rep) {
        int e = rep * 512 + t;      // 2048 uint4 slots
        int dp = e >> 4, seg = e & 15;
        *(uint4*)&sm.fin.Ws[dp * LWT + seg * 8] = *(const uint4*)&WlT[dp * DD + seg * 8];
    }
#pragma unroll
    for (int j = 0; j < 2; ++j)
#pragma unroll
        for (int r = 0; r < 4; ++r)
            sm.fin.Hs[(wr + q * 4 + r) * LWT + wc + j * 16 + r16] = f2bf(acc[j][r]);
    __syncthreads();

    f32x4 c2[2];
    c2[0] = (f32x4){0.f, 0.f, 0.f, 0.f};
    c2[1] = (f32x4){0.f, 0.f, 0.f, 0.f};
#pragma unroll
    for (int ksp = 0; ksp < 4; ++ksp) {
        int ko = ksp * 32 + q * 8;
        bf16x8 a0 = *(const bf16x8*)&sm.fin.Hs[(wr + r16) * LWT + ko];
        bf16x8 b0 = *(const bf16x8*)&sm.fin.Ws[(wc + r16) * LWT + ko];
        bf16x8 b1v = *(const bf16x8*)&sm.fin.Ws[(wc + 16 + r16) * LWT + ko];
        c2[0] = __builtin_amdgcn_mfma_f32_16x16x32_bf16(a0, b0, c2[0], 0, 0, 0);
        c2[1] = __builtin_amdgcn_mfma_f32_16x16x32_bf16(a0, b1v, c2[1], 0, 0, 0);
    }
    float v[2][4];
#pragma unroll
    for (int j = 0; j < 2; ++j)
#pragma unroll
        for (int r = 0; r < 4; ++r)
            v[j][r] = fmaxf(c2[j][r], 0.f);

    int c0 = wc + r16, c1 = wc + 16 + r16;
    float s1c0 = s1[c0], s1c1 = s1[c1], b1c0 = b1[c0], b1c1 = b1[c1];
    float s2c0 = s2[c0], s2c1 = s2[c1], b2c0 = b2[c0], b2c1 = b2[c1];
    int g4 = (w & 3) * 32;          // reduction group offset

#pragma unroll
    for (int r = 0; r < 4; ++r) {
        float s = v[0][r] + v[1][r];
        float qq = v[0][r] * v[0][r] + v[1][r] * v[1][r];
#pragma unroll
        for (int off = 1; off < 16; off <<= 1) {
            s += __shfl_xor(s, off);
            qq += __shfl_xor(qq, off);
        }
        if (r16 == 0) {
            int row = wr + q * 4 + r;
            redS[g4 + row] = s;
            redQ[g4 + row] = qq;
        }
    }
    __syncthreads();
    if (t < 32) {
        float s = redS[t] + redS[32 + t] + redS[64 + t] + redS[96 + t];
        float qq = redQ[t] + redQ[32 + t] + redQ[64 + t] + redQ[96 + t];
        float mu = s * (1.f / 128.f);
        float var = qq * (1.f / 128.f) - mu * mu;
        MV[t] = make_float2(mu, 1.f / sqrtf(var + 1e-5f));
    }
    __syncthreads();
    float y[2][4];
#pragma unroll
    for (int r = 0; r < 4; ++r) {
        float2 mv = MV[wr + q * 4 + r];
        y[0][r] = (v[0][r] - mv.x) * mv.y * s1c0 + b1c0;
        y[1][r] = (v[1][r] - mv.x) * mv.y * s1c1 + b1c1;
    }
    __syncthreads();
#pragma unroll
    for (int r = 0; r < 4; ++r) {
        float s = y[0][r] + y[1][r];
        float qq = y[0][r] * y[0][r] + y[1][r] * y[1][r];
#pragma unroll
        for (int off = 1; off < 16; off <<= 1) {
            s += __shfl_xor(s, off);
            qq += __shfl_xor(qq, off);
        }
        if (r16 == 0) {
            int row = wr + q * 4 + r;
            redS[g4 + row] = s;
            redQ[g4 + row] = qq;
        }
    }
    __syncthreads();
    if (t < 32) {
        float s = redS[t] + redS[32 + t] + redS[64 + t] + redS[96 + t];
        float qq = redQ[t] + redQ[32 + t] + redQ[64 + t] + redQ[96 + t];
        float mu = s * (1.f / 128.f);
        float var = qq * (1.f / 128.f) - mu * mu;
        MV[t] = make_float2(mu, 1.f / sqrtf(var + 1e-5f));
    }
    __syncthreads();
#pragma unroll
    for (int r = 0; r < 4; ++r) {
        float2 mv = MV[wr + q * 4 + r];
        size_t o = ((size_t)b * NN + R0 + wr + q * 4 + r) * DD;
        out[o + c0] = (y[0][r] - mv.x) * mv.y * s2c0 + b2c0;
        out[o + c1] = (y[1][r] - mv.x) * mv.y * s2c1 + b2c1;
    }
}

extern "C" void kernel_launch(void* const* d_in, const int* in_sizes, int n_in,
                              void* d_out, int out_size, void* d_ws, size_t ws_size,
                              hipStream_t stream) {
    const float* X = (const float*)d_in[0];
    const float* Msk = (const float*)d_in[1];
    const float* Astat = (const float*)d_in[2];
    const int* Mm = (const int*)d_in[3];
    const float* rel = (const float*)d_in[4];
    const float* Wproj = (const float*)d_in[5];
    const float* Wq = (const float*)d_in[6];
    const float* Wk = (const float*)d_in[7];
    const float* Wlin = (const float*)d_in[8];
    const float* s1 = (const float*)d_in[9];
    const float* b1 = (const float*)d_in[10];
    const float* s2 = (const float*)d_in[11];
    const float* b2 = (const float*)d_in[12];

    float* outMain = (float*)d_out;                       // (B,N,D)
    float* Afuse = outMain + (size_t)BB * NN * DD;        // (B,N,N)

    float* w_ = (float*)d_ws;
    float* Wpq = w_;                                      // 4096 f
    float* Wpk = w_ + 4096;                               // 4096 f
    u16* WlT = (u16*)(w_ + 8192);                         // 16384 u16
    u16* Qb = (u16*)(w_ + 16384);                         // 2097152 u16
    u16* Kb = (u16*)(w_ + 1064960);                       // 2097152 u16
    u16* HnT = (u16*)(w_ + 2113536);                      // 2097152 u16
    u16* lgh = (u16*)(w_ + 3162112);                      // 4194304 u16 (f16)
    u16* am = (u16*)(w_ + 5259264);                       // 4194304 u16 (bf16)
    u16* Ebuf = (u16*)(w_ + 7356416);                     // 33554432 u16 (bf16)
    float* part = w_ + 24133632;                          // 196608 f

    prep_kernel<<<dim3(4192), dim3(256), 0, stream>>>(
        Astat, Mm, Wproj, Wq, Wk, Wlin, lgh, am, Wpq, Wpk, WlT);
    proj3_kernel<<<dim3(512), dim3(256), 0, stream>>>(X, Msk, Wproj, Wpq, Wpk, HnT, Qb, Kb);

    stats_kernel<<<dim3(4, 64, 8), dim3(256), 0, stream>>>(
        Qb, Kb, lgh, am, rel, Ebuf, part);
    prop_kernel<<<dim3(64, 8), dim3(512), 0, stream>>>(
        Ebuf, am, part, rel, HnT, WlT, s1, b1, s2, b2, Afuse, outMain);
}